// Round 1
// baseline (355.233 us; speedup 1.0000x reference)
//
#include <hip/hip_runtime.h>

#define EPS 1e-5f

__device__ __forceinline__ float wave_sum64(float v) {
    #pragma unroll
    for (int off = 32; off > 0; off >>= 1) v += __shfl_xor(v, off, 64);
    return v;
}
__device__ __forceinline__ float wave_max64(float v) {
    #pragma unroll
    for (int off = 32; off > 0; off >>= 1) v = fmaxf(v, __shfl_xor(v, off, 64));
    return v;
}

// ---------------- Kernel 1: node branch + sr/sc ----------------
// grid = B*N = 4096, block = 64 (one wave per row)
__global__ __launch_bounds__(64) void node_kernel(
    const float* __restrict__ node, const float* __restrict__ ln1_g, const float* __restrict__ ln1_b,
    const float* __restrict__ Wn, const float* __restrict__ bn, const float* __restrict__ attn_A,
    float* __restrict__ h_out, float* __restrict__ sr_out, float* __restrict__ sc_out)
{
    const int row  = blockIdx.x;      // b*N + i
    const int lane = threadIdx.x;     // 0..63

    float x = node[(long)row * 64 + lane];
    float mu  = wave_sum64(x) * (1.0f / 64.0f);
    float d   = x - mu;
    float var = wave_sum64(d * d) * (1.0f / 64.0f);
    float xln = d * rsqrtf(var + EPS) * ln1_g[lane] + ln1_b[lane];

    __shared__ float xs[64];
    xs[lane] = xln;
    __syncthreads();

    float acc = bn[lane];
    const float* wrow = Wn + lane * 64;
    #pragma unroll
    for (int f = 0; f < 64; ++f) acc = fmaf(xs[f], wrow[f], acc);
    h_out[(long)row * 64 + lane] = acc;

    // sr/sc: reduce h[head*16+x] * a_{row,col}[x] over x within each 16-lane group
    const int xidx = lane & 15;
    float ar = 0.f, ac = 0.f;
    #pragma unroll
    for (int hh = 0; hh < 4; ++hh) {
        ar += attn_A[hh * 48 + xidx];
        ac += attn_A[hh * 48 + 16 + xidx];
    }
    float pr = acc * ar, pc = acc * ac;
    #pragma unroll
    for (int off = 8; off > 0; off >>= 1) {
        pr += __shfl_down(pr, off, 16);
        pc += __shfl_down(pc, off, 16);
    }
    if (xidx == 0) {
        const int head = lane >> 4;
        sr_out[(long)row * 4 + head] = pr;
        sc_out[(long)row * 4 + head] = pc;
    }
}

// ---------------- Kernel 2: edge MLP + se + adj passthrough ----------------
// one thread per (b,i,j) row of E=16; grid = 2097152/256 = 8192
__global__ __launch_bounds__(256) void edge_kernel(
    const float* __restrict__ edge, const int* __restrict__ adj,
    const float* __restrict__ ln2_g, const float* __restrict__ ln2_b,
    const float* __restrict__ We1, const float* __restrict__ be1,
    const float* __restrict__ We2, const float* __restrict__ be2,
    const float* __restrict__ lne_g, const float* __restrict__ lne_b,
    const float* __restrict__ attn_A,
    float* __restrict__ e_out, float* __restrict__ adj_out, float* __restrict__ se_out)
{
    const long r = (long)blockIdx.x * 256 + threadIdx.x;   // 0 .. 2M-1

    const float4* ep = (const float4*)(edge + r * 16);
    float4 v0 = ep[0], v1 = ep[1], v2 = ep[2], v3 = ep[3];
    float ev[16] = { v0.x, v0.y, v0.z, v0.w, v1.x, v1.y, v1.z, v1.w,
                     v2.x, v2.y, v2.z, v2.w, v3.x, v3.y, v3.z, v3.w };

    // LN over E=16
    float mu = 0.f;
    #pragma unroll
    for (int i = 0; i < 16; ++i) mu += ev[i];
    mu *= (1.0f / 16.0f);
    float var = 0.f;
    #pragma unroll
    for (int i = 0; i < 16; ++i) { float d = ev[i] - mu; var += d * d; }
    var *= (1.0f / 16.0f);
    const float rs = rsqrtf(var + EPS);

    float xln[16];
    #pragma unroll
    for (int i = 0; i < 16; ++i) xln[i] = (ev[i] - mu) * rs * ln2_g[i] + ln2_b[i];

    // MLP: 16 -> 32 (celu) -> 16
    float act[32];
    #pragma unroll
    for (int k = 0; k < 32; ++k) {
        float a = be1[k];
        #pragma unroll
        for (int i = 0; i < 16; ++i) a = fmaf(xln[i], We1[k * 16 + i], a);
        act[k] = (a > 0.f) ? a : (__expf(a) - 1.f);   // celu, alpha=1
    }

    float eo[16];
    #pragma unroll
    for (int j = 0; j < 16; ++j) {
        float a = be2[j];
        #pragma unroll
        for (int k = 0; k < 32; ++k) a = fmaf(act[k], We2[j * 32 + k], a);
        eo[j] = a + ev[j];                             // residual with original edge
    }

    // final LN over E=16
    float mu2 = 0.f;
    #pragma unroll
    for (int j = 0; j < 16; ++j) mu2 += eo[j];
    mu2 *= (1.0f / 16.0f);
    float var2 = 0.f;
    #pragma unroll
    for (int j = 0; j < 16; ++j) { float d = eo[j] - mu2; var2 += d * d; }
    var2 *= (1.0f / 16.0f);
    const float rs2 = rsqrtf(var2 + EPS);

    float se = 0.f;
    #pragma unroll
    for (int j = 0; j < 16; ++j) {
        float ae = attn_A[32 + j] + attn_A[48 + 32 + j] + attn_A[96 + 32 + j] + attn_A[144 + 32 + j];
        float o = (eo[j] - mu2) * rs2 * lne_g[j] + lne_b[j];
        eo[j] = o;
        se = fmaf(o, ae, se);
    }

    float4* op = (float4*)(e_out + r * 16);
    op[0] = make_float4(eo[0], eo[1], eo[2], eo[3]);
    op[1] = make_float4(eo[4], eo[5], eo[6], eo[7]);
    op[2] = make_float4(eo[8], eo[9], eo[10], eo[11]);
    op[3] = make_float4(eo[12], eo[13], eo[14], eo[15]);

    se_out[r]  = se;
    adj_out[r] = (float)adj[r];
}

// ---------------- Kernel 3: attention softmax + msg + output proj + LN ----------------
// grid = B*N = 4096, block = 256 (4 waves)
__global__ __launch_bounds__(256) void attn_kernel(
    const float* __restrict__ h_ws, const float* __restrict__ sr_ws, const float* __restrict__ sc_ws,
    const float* __restrict__ se_ws, const int* __restrict__ adj,
    const float* __restrict__ node, const float* __restrict__ Wo, const float* __restrict__ bo,
    const float* __restrict__ lno_g, const float* __restrict__ lno_b,
    float* __restrict__ out)
{
    const int bi   = blockIdx.x;        // b*N + i
    const int b    = bi >> 9;
    const int tid  = threadIdx.x;       // 0..255
    const int wave = tid >> 6;
    const int lane = tid & 63;

    __shared__ float lg[4][520];        // logits -> coeffs, padded (520%32=8) to break bank alias
    __shared__ float msg_p[4][64];
    __shared__ float msg_l[64];

    const float sr0 = sr_ws[(long)bi * 4 + 0];
    const float sr1 = sr_ws[(long)bi * 4 + 1];
    const float sr2 = sr_ws[(long)bi * 4 + 2];
    const float sr3 = sr_ws[(long)bi * 4 + 3];

    const float*  se_row  = se_ws + (long)bi * 512;
    const int*    adj_row = adj   + (long)bi * 512;
    const float4* sc4     = (const float4*)(sc_ws + (long)b * 512 * 4);

    for (int j = tid; j < 512; j += 256) {
        float4 s = sc4[j];
        float  se = se_row[j];
        bool   m  = (adj_row[j] != 0);
        float l0 = m ? (sr0 + s.x + se) : -1e9f;
        float l1 = m ? (sr1 + s.y + se) : -1e9f;
        float l2 = m ? (sr2 + s.z + se) : -1e9f;
        float l3 = m ? (sr3 + s.w + se) : -1e9f;
        l0 = (l0 > 0.f) ? l0 : 0.2f * l0;  l0 = fminf(fmaxf(l0, -1e9f), 1e9f);
        l1 = (l1 > 0.f) ? l1 : 0.2f * l1;  l1 = fminf(fmaxf(l1, -1e9f), 1e9f);
        l2 = (l2 > 0.f) ? l2 : 0.2f * l2;  l2 = fminf(fmaxf(l2, -1e9f), 1e9f);
        l3 = (l3 > 0.f) ? l3 : 0.2f * l3;  l3 = fminf(fmaxf(l3, -1e9f), 1e9f);
        lg[0][j] = l0; lg[1][j] = l1; lg[2][j] = l2; lg[3][j] = l3;
    }
    __syncthreads();

    // softmax over j, one wave per head
    {
        float* L = lg[wave];
        float v[8];
        float m = -1e30f;
        #pragma unroll
        for (int k = 0; k < 8; ++k) { v[k] = L[lane + k * 64]; m = fmaxf(m, v[k]); }
        m = wave_max64(m);
        float s = 0.f;
        #pragma unroll
        for (int k = 0; k < 8; ++k) { v[k] = __expf(v[k] - m); s += v[k]; }
        s = wave_sum64(s);
        const float inv = 1.0f / s;
        #pragma unroll
        for (int k = 0; k < 8; ++k) L[lane + k * 64] = v[k] * inv;
    }
    __syncthreads();

    // msg[f] = sum_j h[b,j,f] * coeff[head(f)][j] ; each wave does a 128-wide j chunk
    {
        const int f    = lane;
        const int head = f >> 4;
        const float* hb = h_ws + (long)b * 512 * 64;
        float acc = 0.f;
        const int j0 = wave * 128;
        #pragma unroll 4
        for (int j = j0; j < j0 + 128; ++j)
            acc = fmaf(hb[(long)j * 64 + f], lg[head][j], acc);
        msg_p[wave][lane] = acc;
    }
    __syncthreads();

    if (tid < 64) {
        msg_l[lane] = msg_p[0][lane] + msg_p[1][lane] + msg_p[2][lane] + msg_p[3][lane];
    }
    __syncthreads();

    if (tid < 64) {
        float o = bo[lane];
        const float* wrow = Wo + lane * 64;
        #pragma unroll
        for (int ff = 0; ff < 64; ++ff) o = fmaf(msg_l[ff], wrow[ff], o);
        o += node[(long)bi * 64 + lane];          // residual
        o = (o > 0.f) ? o : 0.2f * o;             // leaky
        float mu  = wave_sum64(o) * (1.0f / 64.0f);
        float d   = o - mu;
        float var = wave_sum64(d * d) * (1.0f / 64.0f);
        out[(long)bi * 64 + lane] = d * rsqrtf(var + EPS) * lno_g[lane] + lno_b[lane];
    }
}

extern "C" void kernel_launch(void* const* d_in, const int* in_sizes, int n_in,
                              void* d_out, int out_size, void* d_ws, size_t ws_size,
                              hipStream_t stream) {
    const float* node   = (const float*)d_in[0];
    const float* edge   = (const float*)d_in[1];
    const int*   adj    = (const int*)  d_in[2];
    const float* ln1_g  = (const float*)d_in[3];
    const float* ln1_b  = (const float*)d_in[4];
    const float* Wn     = (const float*)d_in[5];
    const float* bn     = (const float*)d_in[6];
    const float* ln2_g  = (const float*)d_in[7];
    const float* ln2_b  = (const float*)d_in[8];
    const float* We1    = (const float*)d_in[9];
    const float* be1    = (const float*)d_in[10];
    const float* We2    = (const float*)d_in[11];
    const float* be2    = (const float*)d_in[12];
    const float* lne_g  = (const float*)d_in[13];
    const float* lne_b  = (const float*)d_in[14];
    const float* attn_A = (const float*)d_in[15];
    const float* Wo     = (const float*)d_in[16];
    const float* bo     = (const float*)d_in[17];
    const float* lno_g  = (const float*)d_in[18];
    const float* lno_b  = (const float*)d_in[19];

    // outputs: out (8*512*64) || e (8*512*512*16) || adj (8*512*512) as float
    float* out_p  = (float*)d_out;
    float* e_out  = out_p + 262144;
    float* adj_o  = e_out + 33554432;

    // workspace: h (262144) | sr (16384) | sc (16384) | se (2097152)  ~9.6 MB
    float* ws    = (float*)d_ws;
    float* h_ws  = ws;
    float* sr_ws = ws + 262144;
    float* sc_ws = ws + 278528;
    float* se_ws = ws + 294912;

    node_kernel<<<4096, 64, 0, stream>>>(node, ln1_g, ln1_b, Wn, bn, attn_A, h_ws, sr_ws, sc_ws);
    edge_kernel<<<8192, 256, 0, stream>>>(edge, adj, ln2_g, ln2_b, We1, be1, We2, be2,
                                          lne_g, lne_b, attn_A, e_out, adj_o, se_ws);
    attn_kernel<<<4096, 256, 0, stream>>>(h_ws, sr_ws, sc_ws, se_ws, adj, node,
                                          Wo, bo, lno_g, lno_b, out_p);
}

// Round 2
// 344.697 us; speedup vs baseline: 1.0306x; 1.0306x over previous
//
#include <hip/hip_runtime.h>

#define EPS 1e-5f

__device__ __forceinline__ float wave_sum64(float v) {
    #pragma unroll
    for (int off = 32; off > 0; off >>= 1) v += __shfl_xor(v, off, 64);
    return v;
}
__device__ __forceinline__ float wave_max64(float v) {
    #pragma unroll
    for (int off = 32; off > 0; off >>= 1) v = fmaxf(v, __shfl_xor(v, off, 64));
    return v;
}

// ---------------- Kernel 1: node branch + sr/sc ----------------
// grid = B*N = 4096, block = 64 (one wave per row)
__global__ __launch_bounds__(64) void node_kernel(
    const float* __restrict__ node, const float* __restrict__ ln1_g, const float* __restrict__ ln1_b,
    const float* __restrict__ Wn, const float* __restrict__ bn, const float* __restrict__ attn_A,
    float* __restrict__ h_out, float* __restrict__ sr_out, float* __restrict__ sc_out)
{
    const int row  = blockIdx.x;      // b*N + i
    const int lane = threadIdx.x;     // 0..63

    float x = node[(long)row * 64 + lane];
    float mu  = wave_sum64(x) * (1.0f / 64.0f);
    float d   = x - mu;
    float var = wave_sum64(d * d) * (1.0f / 64.0f);
    float xln = d * rsqrtf(var + EPS) * ln1_g[lane] + ln1_b[lane];

    __shared__ float xs[64];
    xs[lane] = xln;
    __syncthreads();

    float acc = bn[lane];
    const float* wrow = Wn + lane * 64;
    #pragma unroll
    for (int f = 0; f < 64; ++f) acc = fmaf(xs[f], wrow[f], acc);
    h_out[(long)row * 64 + lane] = acc;

    // sr/sc: reduce h[head*16+x] * a_{row,col}[x] over x within each 16-lane group
    const int xidx = lane & 15;
    float ar = 0.f, ac = 0.f;
    #pragma unroll
    for (int hh = 0; hh < 4; ++hh) {
        ar += attn_A[hh * 48 + xidx];
        ac += attn_A[hh * 48 + 16 + xidx];
    }
    float pr = acc * ar, pc = acc * ac;
    #pragma unroll
    for (int off = 8; off > 0; off >>= 1) {
        pr += __shfl_down(pr, off, 16);
        pc += __shfl_down(pc, off, 16);
    }
    if (xidx == 0) {
        const int head = lane >> 4;
        sr_out[(long)row * 4 + head] = pr;
        sc_out[(long)row * 4 + head] = pc;
    }
}

// ---------------- Kernel 2: edge MLP + se + adj passthrough ----------------
// one thread per (b,i,j) row of E=16; grid = 2097152/256 = 8192
// (256,4): allow up to 128 VGPRs (was 52 -> serialized FMA chains, latency-bound)
__global__ __launch_bounds__(256, 4) void edge_kernel(
    const float* __restrict__ edge, const int* __restrict__ adj,
    const float* __restrict__ ln2_g, const float* __restrict__ ln2_b,
    const float* __restrict__ We1, const float* __restrict__ be1,
    const float* __restrict__ We2, const float* __restrict__ be2,
    const float* __restrict__ lne_g, const float* __restrict__ lne_b,
    const float* __restrict__ attn_A,
    float* __restrict__ e_out, float* __restrict__ adj_out, float* __restrict__ se_out)
{
    const long r = (long)blockIdx.x * 256 + threadIdx.x;   // 0 .. 2M-1

    const float4* ep = (const float4*)(edge + r * 16);
    float4 v0 = ep[0], v1 = ep[1], v2 = ep[2], v3 = ep[3];
    float ev[16] = { v0.x, v0.y, v0.z, v0.w, v1.x, v1.y, v1.z, v1.w,
                     v2.x, v2.y, v2.z, v2.w, v3.x, v3.y, v3.z, v3.w };

    // a_edge (uniform) — hoisted out of the tail loop
    float ae[16];
    #pragma unroll
    for (int j = 0; j < 16; ++j)
        ae[j] = attn_A[32 + j] + attn_A[48 + 32 + j] + attn_A[96 + 32 + j] + attn_A[144 + 32 + j];

    // LN over E=16
    float mu = 0.f;
    #pragma unroll
    for (int i = 0; i < 16; ++i) mu += ev[i];
    mu *= (1.0f / 16.0f);
    float var = 0.f;
    #pragma unroll
    for (int i = 0; i < 16; ++i) { float d = ev[i] - mu; var += d * d; }
    var *= (1.0f / 16.0f);
    const float rs = rsqrtf(var + EPS);

    float xln[16];
    #pragma unroll
    for (int i = 0; i < 16; ++i) xln[i] = (ev[i] - mu) * rs * ln2_g[i] + ln2_b[i];

    // MLP: 16 -> 32 (celu) -> 16
    float act[32];
    #pragma unroll
    for (int k = 0; k < 32; ++k) {
        float a = be1[k];
        #pragma unroll
        for (int i = 0; i < 16; ++i) a = fmaf(xln[i], We1[k * 16 + i], a);
        act[k] = (a > 0.f) ? a : (__expf(a) - 1.f);   // celu, alpha=1
    }

    float eo[16];
    #pragma unroll
    for (int j = 0; j < 16; ++j) {
        float a = be2[j];
        #pragma unroll
        for (int k = 0; k < 32; ++k) a = fmaf(act[k], We2[j * 32 + k], a);
        eo[j] = a + ev[j];                             // residual with original edge
    }

    // final LN over E=16
    float mu2 = 0.f;
    #pragma unroll
    for (int j = 0; j < 16; ++j) mu2 += eo[j];
    mu2 *= (1.0f / 16.0f);
    float var2 = 0.f;
    #pragma unroll
    for (int j = 0; j < 16; ++j) { float d = eo[j] - mu2; var2 += d * d; }
    var2 *= (1.0f / 16.0f);
    const float rs2 = rsqrtf(var2 + EPS);

    float se = 0.f;
    #pragma unroll
    for (int j = 0; j < 16; ++j) {
        float o = (eo[j] - mu2) * rs2 * lne_g[j] + lne_b[j];
        eo[j] = o;
        se = fmaf(o, ae[j], se);
    }

    float4* op = (float4*)(e_out + r * 16);
    op[0] = make_float4(eo[0], eo[1], eo[2], eo[3]);
    op[1] = make_float4(eo[4], eo[5], eo[6], eo[7]);
    op[2] = make_float4(eo[8], eo[9], eo[10], eo[11]);
    op[3] = make_float4(eo[12], eo[13], eo[14], eo[15]);

    se_out[r]  = se;
    adj_out[r] = (float)adj[r];
}

// ---------------- Kernel 3: attention softmax + msg + output proj + LN ----------------
// G=4 rows (i values) per block; grid = B*N/G = 1024, block = 256 (4 waves)
#define G 4
__global__ __launch_bounds__(256, 4) void attn_kernel(
    const float* __restrict__ h_ws, const float* __restrict__ sr_ws, const float* __restrict__ sc_ws,
    const float* __restrict__ se_ws, const int* __restrict__ adj,
    const float* __restrict__ node, const float* __restrict__ Wo, const float* __restrict__ bo,
    const float* __restrict__ lno_g, const float* __restrict__ lno_b,
    float* __restrict__ out)
{
    const int bi0  = blockIdx.x * G;    // first row (b*N + i); N%G==0 so same batch
    const int b    = bi0 >> 9;
    const int tid  = threadIdx.x;       // 0..255
    const int wave = tid >> 6;
    const int lane = tid & 63;

    // stride 516: head-stride 516 %32 = 4 banks -> 4 distinct head addrs hit distinct banks
    __shared__ float coef[G][4][516];
    __shared__ float hpart[4][G][64];
    __shared__ float msg_s[G][64];

    const float4* sc4 = (const float4*)(sc_ws + (long)b * 512 * 4);

    // ---- Phase 1: logits for G rows ----
    #pragma unroll
    for (int r = 0; r < G; ++r) {
        const int row = bi0 + r;
        const float sr0 = sr_ws[(long)row * 4 + 0];
        const float sr1 = sr_ws[(long)row * 4 + 1];
        const float sr2 = sr_ws[(long)row * 4 + 2];
        const float sr3 = sr_ws[(long)row * 4 + 3];
        const float* se_row  = se_ws + (long)row * 512;
        const int*   adj_row = adj   + (long)row * 512;
        #pragma unroll
        for (int half = 0; half < 2; ++half) {
            const int j = half * 256 + tid;
            float4 s = sc4[j];
            float  se = se_row[j];
            bool   m  = (adj_row[j] != 0);
            float l0 = m ? (sr0 + s.x + se) : -1e9f;
            float l1 = m ? (sr1 + s.y + se) : -1e9f;
            float l2 = m ? (sr2 + s.z + se) : -1e9f;
            float l3 = m ? (sr3 + s.w + se) : -1e9f;
            l0 = (l0 > 0.f) ? l0 : 0.2f * l0;  l0 = fminf(fmaxf(l0, -1e9f), 1e9f);
            l1 = (l1 > 0.f) ? l1 : 0.2f * l1;  l1 = fminf(fmaxf(l1, -1e9f), 1e9f);
            l2 = (l2 > 0.f) ? l2 : 0.2f * l2;  l2 = fminf(fmaxf(l2, -1e9f), 1e9f);
            l3 = (l3 > 0.f) ? l3 : 0.2f * l3;  l3 = fminf(fmaxf(l3, -1e9f), 1e9f);
            coef[r][0][j] = l0; coef[r][1][j] = l1; coef[r][2][j] = l2; coef[r][3][j] = l3;
        }
    }
    __syncthreads();

    // ---- Phase 2: softmax over j; 16 (r,h) pairs, 4 per wave ----
    #pragma unroll
    for (int q = 0; q < 4; ++q) {
        const int p = q * 4 + wave;     // 0..15
        float* L = coef[p >> 2][p & 3];
        float v[8];
        float m = -1e30f;
        #pragma unroll
        for (int k = 0; k < 8; ++k) { v[k] = L[lane + k * 64]; m = fmaxf(m, v[k]); }
        m = wave_max64(m);
        float s = 0.f;
        #pragma unroll
        for (int k = 0; k < 8; ++k) { v[k] = __expf(v[k] - m); s += v[k]; }
        s = wave_sum64(s);
        const float inv = 1.0f / s;
        #pragma unroll
        for (int k = 0; k < 8; ++k) L[lane + k * 64] = v[k] * inv;
    }
    __syncthreads();

    // ---- Phase 3: msg partials; each wave owns a 128-wide j chunk, reuses h for all G rows ----
    {
        const int head = lane >> 4;
        const float* hb = h_ws + (long)b * 512 * 64;
        float a0 = 0.f, a1 = 0.f, a2 = 0.f, a3 = 0.f;
        const int j0 = wave * 128;
        #pragma unroll 8
        for (int j = j0; j < j0 + 128; ++j) {
            float hv = hb[(long)j * 64 + lane];
            a0 = fmaf(hv, coef[0][head][j], a0);
            a1 = fmaf(hv, coef[1][head][j], a1);
            a2 = fmaf(hv, coef[2][head][j], a2);
            a3 = fmaf(hv, coef[3][head][j], a3);
        }
        hpart[wave][0][lane] = a0;
        hpart[wave][1][lane] = a1;
        hpart[wave][2][lane] = a2;
        hpart[wave][3][lane] = a3;
    }
    __syncthreads();

    // ---- Phase 4: wave r finishes row r: reduce partials, project, residual, leaky, LN ----
    {
        const int r   = wave;
        const int row = bi0 + r;
        float m = hpart[0][r][lane] + hpart[1][r][lane] + hpart[2][r][lane] + hpart[3][r][lane];
        msg_s[r][lane] = m;          // within-wave RAW; lgkmcnt handles ordering

        float o = bo[lane];
        const float* wrow = Wo + lane * 64;
        #pragma unroll
        for (int ff = 0; ff < 64; ++ff) o = fmaf(msg_s[r][ff], wrow[ff], o);
        o += node[(long)row * 64 + lane];         // residual
        o = (o > 0.f) ? o : 0.2f * o;             // leaky
        float mu  = wave_sum64(o) * (1.0f / 64.0f);
        float d   = o - mu;
        float var = wave_sum64(d * d) * (1.0f / 64.0f);
        out[(long)row * 64 + lane] = d * rsqrtf(var + EPS) * lno_g[lane] + lno_b[lane];
    }
}

extern "C" void kernel_launch(void* const* d_in, const int* in_sizes, int n_in,
                              void* d_out, int out_size, void* d_ws, size_t ws_size,
                              hipStream_t stream) {
    const float* node   = (const float*)d_in[0];
    const float* edge   = (const float*)d_in[1];
    const int*   adj    = (const int*)  d_in[2];
    const float* ln1_g  = (const float*)d_in[3];
    const float* ln1_b  = (const float*)d_in[4];
    const float* Wn     = (const float*)d_in[5];
    const float* bn     = (const float*)d_in[6];
    const float* ln2_g  = (const float*)d_in[7];
    const float* ln2_b  = (const float*)d_in[8];
    const float* We1    = (const float*)d_in[9];
    const float* be1    = (const float*)d_in[10];
    const float* We2    = (const float*)d_in[11];
    const float* be2    = (const float*)d_in[12];
    const float* lne_g  = (const float*)d_in[13];
    const float* lne_b  = (const float*)d_in[14];
    const float* attn_A = (const float*)d_in[15];
    const float* Wo     = (const float*)d_in[16];
    const float* bo     = (const float*)d_in[17];
    const float* lno_g  = (const float*)d_in[18];
    const float* lno_b  = (const float*)d_in[19];

    // outputs: out (8*512*64) || e (8*512*512*16) || adj (8*512*512) as float
    float* out_p  = (float*)d_out;
    float* e_out  = out_p + 262144;
    float* adj_o  = e_out + 33554432;

    // workspace: h (262144) | sr (16384) | sc (16384) | se (2097152)  ~9.6 MB
    float* ws    = (float*)d_ws;
    float* h_ws  = ws;
    float* sr_ws = ws + 262144;
    float* sc_ws = ws + 278528;
    float* se_ws = ws + 294912;

    node_kernel<<<4096, 64, 0, stream>>>(node, ln1_g, ln1_b, Wn, bn, attn_A, h_ws, sr_ws, sc_ws);
    edge_kernel<<<8192, 256, 0, stream>>>(edge, adj, ln2_g, ln2_b, We1, be1, We2, be2,
                                          lne_g, lne_b, attn_A, e_out, adj_o, se_ws);
    attn_kernel<<<1024, 256, 0, stream>>>(h_ws, sr_ws, sc_ws, se_ws, adj, node,
                                          Wo, bo, lno_g, lno_b, out_p);
}

// Round 3
// 329.622 us; speedup vs baseline: 1.0777x; 1.0457x over previous
//
#include <hip/hip_runtime.h>

#define EPS 1e-5f

typedef __attribute__((ext_vector_type(8))) short bfrag;   // 8 bf16 = 4 VGPR (MFMA A/B)
typedef __attribute__((ext_vector_type(4))) float ffrag;   // 4 f32 (MFMA C/D)

union BFU { int i[4]; bfrag v; };

__device__ __forceinline__ float wave_sum64(float v) {
    #pragma unroll
    for (int off = 32; off > 0; off >>= 1) v += __shfl_xor(v, off, 64);
    return v;
}
__device__ __forceinline__ float wave_max64(float v) {
    #pragma unroll
    for (int off = 32; off > 0; off >>= 1) v = fmaxf(v, __shfl_xor(v, off, 64));
    return v;
}

// round-to-nearest-even f32 -> bf16, packed pair
__device__ __forceinline__ int pk_bf16(float a, float b) {
    union { float f; unsigned u; } x, y;
    x.f = a; y.f = b;
    unsigned ra = (x.u + 0x7fffu + ((x.u >> 16) & 1u)) >> 16;
    unsigned rb = (y.u + 0x7fffu + ((y.u >> 16) & 1u)) >> 16;
    return (int)((rb << 16) | (ra & 0xffffu));
}

__device__ __forceinline__ float celu1(float x) {
    return (x > 0.f) ? x : (__expf(x) - 1.f);
}

// ---------------- Kernel 1: node branch + sr/sc ----------------
__global__ __launch_bounds__(64) void node_kernel(
    const float* __restrict__ node, const float* __restrict__ ln1_g, const float* __restrict__ ln1_b,
    const float* __restrict__ Wn, const float* __restrict__ bn, const float* __restrict__ attn_A,
    float* __restrict__ h_out, float* __restrict__ sr_out, float* __restrict__ sc_out)
{
    const int row  = blockIdx.x;
    const int lane = threadIdx.x;

    float x = node[(long)row * 64 + lane];
    float mu  = wave_sum64(x) * (1.0f / 64.0f);
    float d   = x - mu;
    float var = wave_sum64(d * d) * (1.0f / 64.0f);
    float xln = d * rsqrtf(var + EPS) * ln1_g[lane] + ln1_b[lane];

    __shared__ float xs[64];
    xs[lane] = xln;
    __syncthreads();

    float acc = bn[lane];
    const float* wrow = Wn + lane * 64;
    #pragma unroll
    for (int f = 0; f < 64; ++f) acc = fmaf(xs[f], wrow[f], acc);
    h_out[(long)row * 64 + lane] = acc;

    const int xidx = lane & 15;
    float ar = 0.f, ac = 0.f;
    #pragma unroll
    for (int hh = 0; hh < 4; ++hh) {
        ar += attn_A[hh * 48 + xidx];
        ac += attn_A[hh * 48 + 16 + xidx];
    }
    float pr = acc * ar, pc = acc * ac;
    #pragma unroll
    for (int off = 8; off > 0; off >>= 1) {
        pr += __shfl_down(pr, off, 16);
        pc += __shfl_down(pc, off, 16);
    }
    if (xidx == 0) {
        const int head = lane >> 4;
        sr_out[(long)row * 4 + head] = pr;
        sc_out[(long)row * 4 + head] = pc;
    }
}

// ---------------- Kernel 2: edge MLP via MFMA ----------------
// Decomposition: D1 = We1(32x16) @ xln^T(16x64rows), D2 = We2(16x32) @ H^T(32x64rows).
// mfma_f32_16x16x32_bf16: A[m=lane&15][k=quad*8+j], B[k=quad*8+j][n=lane&15],
// D[m=quad*4+reg][n=lane&15]  (layouts per cdna4_isa / learn_hip m89/m120).
// Lane (q,t) at tile nt owns row R=16*nt+t, channel chunk 4q..4q+3 for load,
// residual and D2 output -> no LDS, no transposes; B-frags built with 12 shfl/tile.
__global__ __launch_bounds__(256, 4) void edge_kernel(
    const float* __restrict__ edge, const int* __restrict__ adj,
    const float* __restrict__ ln2_g, const float* __restrict__ ln2_b,
    const float* __restrict__ We1, const float* __restrict__ be1,
    const float* __restrict__ We2, const float* __restrict__ be2,
    const float* __restrict__ lne_g, const float* __restrict__ lne_b,
    const float* __restrict__ attn_A,
    float* __restrict__ e_out, float* __restrict__ adj_out, float* __restrict__ se_out)
{
    const int tid  = threadIdx.x;
    const int wave = tid >> 6;
    const int lane = tid & 63;
    const int q    = lane >> 4;       // quad 0..3
    const int t    = lane & 15;
    const long r0  = (long)blockIdx.x * 256 + wave * 64;   // wave's 64 rows
    const int  c4  = 4 * q;           // this lane's channel chunk

    // ---- per-lane constants (channel chunk c4..c4+3) ----
    const float4 g1  = *(const float4*)(ln2_g + c4);
    const float4 b1  = *(const float4*)(ln2_b + c4);
    const float4 gE  = *(const float4*)(lne_g + c4);
    const float4 bE  = *(const float4*)(lne_b + c4);
    const float4 vb2 = *(const float4*)(be2 + c4);
    const float4 vb1a = *(const float4*)(be1 + c4);        // hidden units 4q+i   (mt=0)
    const float4 vb1b = *(const float4*)(be1 + 16 + c4);   // hidden units 16+4q+i (mt=1)
    float4 ae = make_float4(0.f, 0.f, 0.f, 0.f);
    #pragma unroll
    for (int hh = 0; hh < 4; ++hh) {
        float4 a = *(const float4*)(attn_A + hh * 48 + 32 + c4);
        ae.x += a.x; ae.y += a.y; ae.z += a.z; ae.w += a.w;
    }

    // ---- weight fragments (loaded once, VGPR-resident) ----
    BFU A1[2], A2;
    A1[0].i[0] = A1[0].i[1] = A1[0].i[2] = A1[0].i[3] = 0;
    A1[1].i[0] = A1[1].i[1] = A1[1].i[2] = A1[1].i[3] = 0;
    if (q < 2) {   // K=16 zero-padded to 32: quads 2,3 stay zero
        #pragma unroll
        for (int mt = 0; mt < 2; ++mt) {
            const float* wp = We1 + (16 * mt + t) * 16 + 8 * q;
            float4 w0 = *(const float4*)(wp);
            float4 w1 = *(const float4*)(wp + 4);
            A1[mt].i[0] = pk_bf16(w0.x, w0.y);
            A1[mt].i[1] = pk_bf16(w0.z, w0.w);
            A1[mt].i[2] = pk_bf16(w1.x, w1.y);
            A1[mt].i[3] = pk_bf16(w1.z, w1.w);
        }
    }
    {
        const float* wp = We2 + t * 32 + 8 * q;
        float4 w0 = *(const float4*)(wp);
        float4 w1 = *(const float4*)(wp + 4);
        A2.i[0] = pk_bf16(w0.x, w0.y);
        A2.i[1] = pk_bf16(w0.z, w0.w);
        A2.i[2] = pk_bf16(w1.x, w1.y);
        A2.i[3] = pk_bf16(w1.z, w1.w);
    }

    const int srcA = ((q & 1) << 5) + t;   // B-frag gather sources (always in [0,64))
    const int srcB = srcA + 16;
    const bool lowhalf = (q < 2);

    #pragma unroll
    for (int nt = 0; nt < 4; ++nt) {
        const long R = r0 + 16 * nt + t;          // this lane's row for tile nt
        const float4 v = *(const float4*)(edge + R * 16 + c4);

        // LN over E=16 (row spread across 4 quads, 4 vals each)
        float s1 = v.x + v.y + v.z + v.w;
        float s2 = fmaf(v.x, v.x, fmaf(v.y, v.y, fmaf(v.z, v.z, v.w * v.w)));
        s1 += __shfl_xor(s1, 16, 64); s1 += __shfl_xor(s1, 32, 64);
        s2 += __shfl_xor(s2, 16, 64); s2 += __shfl_xor(s2, 32, 64);
        const float mu = s1 * (1.0f / 16.0f);
        float var = fmaxf(s2 * (1.0f / 16.0f) - mu * mu, 0.f);
        const float rs = rsqrtf(var + EPS);
        const float x0 = (v.x - mu) * rs * g1.x + b1.x;
        const float x1 = (v.y - mu) * rs * g1.y + b1.y;
        const float x2 = (v.z - mu) * rs * g1.z + b1.z;
        const float x3 = (v.w - mu) * rs * g1.w + b1.w;
        const int p0 = pk_bf16(x0, x1), p1 = pk_bf16(x2, x3);

        // B1 fragment: B[k=8q+j][n=t] = xln[row 16nt+t][col 8q+j] (k>=16 -> A1=0, don't care)
        BFU B1;
        B1.i[0] = __shfl(p0, srcA, 64);
        B1.i[1] = __shfl(p1, srcA, 64);
        B1.i[2] = __shfl(p0, srcB, 64);
        B1.i[3] = __shfl(p1, srcB, 64);

        ffrag acc0 = { vb1a.x, vb1a.y, vb1a.z, vb1a.w };   // bias in C
        ffrag acc1 = { vb1b.x, vb1b.y, vb1b.z, vb1b.w };
        acc0 = __builtin_amdgcn_mfma_f32_16x16x32_bf16(A1[0].v, B1.v, acc0, 0, 0, 0);
        acc1 = __builtin_amdgcn_mfma_f32_16x16x32_bf16(A1[1].v, B1.v, acc1, 0, 0, 0);

        // celu, pack hidden units (lane holds units {4q+i} and {16+4q+i} of its row)
        const int c0a = pk_bf16(celu1(acc0[0]), celu1(acc0[1]));
        const int c0b = pk_bf16(celu1(acc0[2]), celu1(acc0[3]));
        const int c1a = pk_bf16(celu1(acc1[0]), celu1(acc1[1]));
        const int c1b = pk_bf16(celu1(acc1[2]), celu1(acc1[3]));

        // B2 fragment: B[k=8q+j][n=t] = H[unit 8q+j][row 16nt+t]
        const int t00 = __shfl(c0a, srcA, 64), t01 = __shfl(c0b, srcA, 64);
        const int t10 = __shfl(c1a, srcA, 64), t11 = __shfl(c1b, srcA, 64);
        const int u00 = __shfl(c0a, srcB, 64), u01 = __shfl(c0b, srcB, 64);
        const int u10 = __shfl(c1a, srcB, 64), u11 = __shfl(c1b, srcB, 64);
        BFU B2;
        B2.i[0] = lowhalf ? t00 : t10;
        B2.i[1] = lowhalf ? t01 : t11;
        B2.i[2] = lowhalf ? u00 : u10;
        B2.i[3] = lowhalf ? u01 : u11;

        ffrag acc2 = { vb2.x, vb2.y, vb2.z, vb2.w };
        acc2 = __builtin_amdgcn_mfma_f32_16x16x32_bf16(A2.v, B2.v, acc2, 0, 0, 0);

        // residual (lane's loaded chunk IS its output chunk) + final LN + se
        const float o0 = acc2[0] + v.x;
        const float o1 = acc2[1] + v.y;
        const float o2 = acc2[2] + v.z;
        const float o3 = acc2[3] + v.w;
        float m1 = o0 + o1 + o2 + o3;
        float m2 = fmaf(o0, o0, fmaf(o1, o1, fmaf(o2, o2, o3 * o3)));
        m1 += __shfl_xor(m1, 16, 64); m1 += __shfl_xor(m1, 32, 64);
        m2 += __shfl_xor(m2, 16, 64); m2 += __shfl_xor(m2, 32, 64);
        const float mu2 = m1 * (1.0f / 16.0f);
        float var2 = fmaxf(m2 * (1.0f / 16.0f) - mu2 * mu2, 0.f);
        const float rs2 = rsqrtf(var2 + EPS);
        const float e0 = (o0 - mu2) * rs2 * gE.x + bE.x;
        const float e1 = (o1 - mu2) * rs2 * gE.y + bE.y;
        const float e2 = (o2 - mu2) * rs2 * gE.z + bE.z;
        const float e3 = (o3 - mu2) * rs2 * gE.w + bE.w;

        *(float4*)(e_out + R * 16 + c4) = make_float4(e0, e1, e2, e3);

        float sep = fmaf(e0, ae.x, fmaf(e1, ae.y, fmaf(e2, ae.z, e3 * ae.w)));
        sep += __shfl_xor(sep, 16, 64); sep += __shfl_xor(sep, 32, 64);
        if (q == 0) se_out[R] = sep;
    }

    // adj passthrough: one row per lane
    adj_out[r0 + lane] = (float)adj[r0 + lane];
}

// ---------------- Kernel 3: attention softmax + msg + output proj + LN ----------------
#define G 4
__global__ __launch_bounds__(256, 4) void attn_kernel(
    const float* __restrict__ h_ws, const float* __restrict__ sr_ws, const float* __restrict__ sc_ws,
    const float* __restrict__ se_ws, const int* __restrict__ adj,
    const float* __restrict__ node, const float* __restrict__ Wo, const float* __restrict__ bo,
    const float* __restrict__ lno_g, const float* __restrict__ lno_b,
    float* __restrict__ out)
{
    const int bi0  = blockIdx.x * G;
    const int b    = bi0 >> 9;
    const int tid  = threadIdx.x;
    const int wave = tid >> 6;
    const int lane = tid & 63;

    __shared__ float coef[G][4][516];
    __shared__ float hpart[4][G][64];
    __shared__ float msg_s[G][64];

    const float4* sc4 = (const float4*)(sc_ws + (long)b * 512 * 4);

    #pragma unroll
    for (int r = 0; r < G; ++r) {
        const int row = bi0 + r;
        const float sr0 = sr_ws[(long)row * 4 + 0];
        const float sr1 = sr_ws[(long)row * 4 + 1];
        const float sr2 = sr_ws[(long)row * 4 + 2];
        const float sr3 = sr_ws[(long)row * 4 + 3];
        const float* se_row  = se_ws + (long)row * 512;
        const int*   adj_row = adj   + (long)row * 512;
        #pragma unroll
        for (int half = 0; half < 2; ++half) {
            const int j = half * 256 + tid;
            float4 s = sc4[j];
            float  se = se_row[j];
            bool   m  = (adj_row[j] != 0);
            float l0 = m ? (sr0 + s.x + se) : -1e9f;
            float l1 = m ? (sr1 + s.y + se) : -1e9f;
            float l2 = m ? (sr2 + s.z + se) : -1e9f;
            float l3 = m ? (sr3 + s.w + se) : -1e9f;
            l0 = (l0 > 0.f) ? l0 : 0.2f * l0;  l0 = fminf(fmaxf(l0, -1e9f), 1e9f);
            l1 = (l1 > 0.f) ? l1 : 0.2f * l1;  l1 = fminf(fmaxf(l1, -1e9f), 1e9f);
            l2 = (l2 > 0.f) ? l2 : 0.2f * l2;  l2 = fminf(fmaxf(l2, -1e9f), 1e9f);
            l3 = (l3 > 0.f) ? l3 : 0.2f * l3;  l3 = fminf(fmaxf(l3, -1e9f), 1e9f);
            coef[r][0][j] = l0; coef[r][1][j] = l1; coef[r][2][j] = l2; coef[r][3][j] = l3;
        }
    }
    __syncthreads();

    #pragma unroll
    for (int qq = 0; qq < 4; ++qq) {
        const int p = qq * 4 + wave;
        float* L = coef[p >> 2][p & 3];
        float v[8];
        float m = -1e30f;
        #pragma unroll
        for (int k = 0; k < 8; ++k) { v[k] = L[lane + k * 64]; m = fmaxf(m, v[k]); }
        m = wave_max64(m);
        float s = 0.f;
        #pragma unroll
        for (int k = 0; k < 8; ++k) { v[k] = __expf(v[k] - m); s += v[k]; }
        s = wave_sum64(s);
        const float inv = 1.0f / s;
        #pragma unroll
        for (int k = 0; k < 8; ++k) L[lane + k * 64] = v[k] * inv;
    }
    __syncthreads();

    {
        const int head = lane >> 4;
        const float* hb = h_ws + (long)b * 512 * 64;
        float a0 = 0.f, a1 = 0.f, a2 = 0.f, a3 = 0.f;
        const int j0 = wave * 128;
        #pragma unroll 8
        for (int j = j0; j < j0 + 128; ++j) {
            float hv = hb[(long)j * 64 + lane];
            a0 = fmaf(hv, coef[0][head][j], a0);
            a1 = fmaf(hv, coef[1][head][j], a1);
            a2 = fmaf(hv, coef[2][head][j], a2);
            a3 = fmaf(hv, coef[3][head][j], a3);
        }
        hpart[wave][0][lane] = a0;
        hpart[wave][1][lane] = a1;
        hpart[wave][2][lane] = a2;
        hpart[wave][3][lane] = a3;
    }
    __syncthreads();

    {
        const int r   = wave;
        const int row = bi0 + r;
        float m = hpart[0][r][lane] + hpart[1][r][lane] + hpart[2][r][lane] + hpart[3][r][lane];
        msg_s[r][lane] = m;

        float o = bo[lane];
        const float* wrow = Wo + lane * 64;
        #pragma unroll
        for (int ff = 0; ff < 64; ++ff) o = fmaf(msg_s[r][ff], wrow[ff], o);
        o += node[(long)row * 64 + lane];
        o = (o > 0.f) ? o : 0.2f * o;
        float mu  = wave_sum64(o) * (1.0f / 64.0f);
        float d   = o - mu;
        float var = wave_sum64(d * d) * (1.0f / 64.0f);
        out[(long)row * 64 + lane] = d * rsqrtf(var + EPS) * lno_g[lane] + lno_b[lane];
    }
}

extern "C" void kernel_launch(void* const* d_in, const int* in_sizes, int n_in,
                              void* d_out, int out_size, void* d_ws, size_t ws_size,
                              hipStream_t stream) {
    const float* node   = (const float*)d_in[0];
    const float* edge   = (const float*)d_in[1];
    const int*   adj    = (const int*)  d_in[2];
    const float* ln1_g  = (const float*)d_in[3];
    const float* ln1_b  = (const float*)d_in[4];
    const float* Wn     = (const float*)d_in[5];
    const float* bn     = (const float*)d_in[6];
    const float* ln2_g  = (const float*)d_in[7];
    const float* ln2_b  = (const float*)d_in[8];
    const float* We1    = (const float*)d_in[9];
    const float* be1    = (const float*)d_in[10];
    const float* We2    = (const float*)d_in[11];
    const float* be2    = (const float*)d_in[12];
    const float* lne_g  = (const float*)d_in[13];
    const float* lne_b  = (const float*)d_in[14];
    const float* attn_A = (const float*)d_in[15];
    const float* Wo     = (const float*)d_in[16];
    const float* bo     = (const float*)d_in[17];
    const float* lno_g  = (const float*)d_in[18];
    const float* lno_b  = (const float*)d_in[19];

    float* out_p  = (float*)d_out;
    float* e_out  = out_p + 262144;
    float* adj_o  = e_out + 33554432;

    float* ws    = (float*)d_ws;
    float* h_ws  = ws;
    float* sr_ws = ws + 262144;
    float* sc_ws = ws + 278528;
    float* se_ws = ws + 294912;

    node_kernel<<<4096, 64, 0, stream>>>(node, ln1_g, ln1_b, Wn, bn, attn_A, h_ws, sr_ws, sc_ws);
    edge_kernel<<<8192, 256, 0, stream>>>(edge, adj, ln2_g, ln2_b, We1, be1, We2, be2,
                                          lne_g, lne_b, attn_A, e_out, adj_o, se_ws);
    attn_kernel<<<1024, 256, 0, stream>>>(h_ws, sr_ws, sc_ws, se_ws, adj, node,
                                          Wo, bo, lno_g, lno_b, out_p);
}